// Round 7
// baseline (826.375 us; speedup 1.0000x reference)
//
#include <hip/hip_runtime.h>
#include <hip/hip_bf16.h>
#include <math.h>

#define BB 4
#define TT 4096
#define DD 1024
#define HH 16
#define DFF 4096
#define KSEL 2048

typedef __attribute__((ext_vector_type(8))) short short8;
typedef __attribute__((ext_vector_type(4))) float f32x4;

__device__ __forceinline__ unsigned short f2bf(float f) {
  union { float f; unsigned int i; } v; v.f = f;
  unsigned int x = v.i;
  unsigned int r = (x + 0x7fffu + ((x >> 16) & 1u)) >> 16;
  return (unsigned short)r;
}

// native 2^x (v_exp_f32) — avoids glibc __exp2f macro collision
__device__ __forceinline__ float exp2g(float x) { return __builtin_amdgcn_exp2f(x); }

// async global->LDS, 16B per lane; lds ptr must be wave-uniform (lane0 = wave base)
__device__ __forceinline__ void gload16(const void* g, void* l) {
  __builtin_amdgcn_global_load_lds(
      (const __attribute__((address_space(1))) void*)g,
      (__attribute__((address_space(3))) void*)l,
      16, 0, 0);
}

// ---------------- merged f32 -> bf16 conversion for all 5 weight tensors ----------------
__global__ void cvt_all_kernel(const float* __restrict__ s0, const float* __restrict__ s1,
                               const float* __restrict__ s2, const float* __restrict__ s3,
                               const float* __restrict__ s4,
                               unsigned short* __restrict__ d0, unsigned short* __restrict__ d1,
                               unsigned short* __restrict__ d2, unsigned short* __restrict__ d3,
                               unsigned short* __restrict__ d4) {
  const long n0 = (long)3 * DD * DD;     // wqkv  3M
  const long n1 = (long)DD * DD;         // wout  1M
  const long n2 = (long)DFF * DD;        // w1/w2/w3  4M each
  long i = ((long)blockIdx.x * 256 + threadIdx.x) * 4;
  const float* src; unsigned short* dst; long off;
  if (i < n0)                    { src = s0; dst = d0; off = i; }
  else if (i < n0 + n1)          { src = s1; dst = d1; off = i - n0; }
  else if (i < n0 + n1 + n2)     { src = s2; dst = d2; off = i - n0 - n1; }
  else if (i < n0 + n1 + 2*n2)   { src = s3; dst = d3; off = i - n0 - n1 - n2; }
  else                           { src = s4; dst = d4; off = i - n0 - n1 - 2*n2; }
  float4 v = *(const float4*)(src + off);
  ushort4 o;
  o.x = f2bf(v.x); o.y = f2bf(v.y); o.z = f2bf(v.z); o.w = f2bf(v.w);
  *(ushort4*)(dst + off) = o;
}

// ---------------- router: f64 dot per token + sigmoid ----------------
__global__ void router_kernel(const float* __restrict__ x,
                              const float* __restrict__ wr,
                              double* __restrict__ dots, float* __restrict__ sig) {
  int token = blockIdx.x * 4 + (threadIdx.x >> 6);
  int lane = threadIdx.x & 63;
  const float* xr = x + (size_t)token * DD;
  double s = 0.0;
  for (int j = lane; j < DD; j += 64)
    s += (double)xr[j] * (double)wr[j];
  for (int o = 32; o > 0; o >>= 1) s += __shfl_down(s, o);
  if (lane == 0) {
    dots[token] = s;
    sig[token] = 1.0f / (1.0f + expf((float)(-s)));
  }
}

// ---------------- rank: count tokens strictly ahead; flag top-k ----------------
__global__ void rank_kernel(const double* __restrict__ dots, int* __restrict__ flags) {
  __shared__ double sd[TT];
  int b = blockIdx.x >> 4;
  int chunk = blockIdx.x & 15;
  const double* drow = dots + (size_t)b * TT;
  for (int j = threadIdx.x; j < TT; j += 256) sd[j] = drow[j];
  __syncthreads();
  int i = chunk * 256 + threadIdx.x;
  double di = sd[i];
  int cnt = 0;
  for (int j = 0; j < TT; ++j) {
    double dj = sd[j];
    cnt += (int)((dj > di) || (dj == di && j < i));
  }
  flags[(size_t)b * TT + i] = (cnt < KSEL) ? 1 : 0;
}

// ---------------- pass-through: copy only UNSELECTED rows of x into out ----------------
// (selected rows are fully overwritten by the gemm_bt<2> scatter later in the stream)
__global__ void copyrow_kernel(const float* __restrict__ x, const int* __restrict__ flags,
                               float* __restrict__ out) {
  int row = blockIdx.x;                 // global token 0 .. BB*TT-1
  if (flags[row]) return;
  const float4* src = (const float4*)(x + (size_t)row * DD);
  float4* dst = (float4*)(out + (size_t)row * DD);
  dst[threadIdx.x] = src[threadIdx.x];  // 256 thr x 16B = 4KB = one row
}

// ---------------- compact: ascending selected GLOBAL indices (b*TT+t) + batch mean ----------------
__global__ void compact_kernel(const int* __restrict__ flags, const float* __restrict__ sig,
                               int* __restrict__ idx, float* __restrict__ means) {
  __shared__ int part[256];
  __shared__ float ssum[256];
  int b = blockIdx.x;
  const int* f = flags + (size_t)b * TT;
  int tid = threadIdx.x;
  int local = 0; float fs = 0.f;
  for (int j = 0; j < 16; ++j) {
    local += f[tid * 16 + j];
    fs += sig[(size_t)b * TT + tid * 16 + j];
  }
  part[tid] = local; ssum[tid] = fs;
  __syncthreads();
  if (tid == 0) {
    int run = 0;
    for (int t = 0; t < 256; ++t) { int c = part[t]; part[t] = run; run += c; }
    float tot = 0.f;
    for (int t = 0; t < 256; ++t) tot += ssum[t];
    means[b] = tot / (float)TT;
  }
  __syncthreads();
  int pos = part[tid];
  for (int j = 0; j < 16; ++j) {
    int t = tid * 16 + j;
    if (f[t]) { idx[(size_t)b * KSEL + pos] = b * TT + t; ++pos; }
  }
}

__global__ void aux_kernel(const float* __restrict__ means, float* __restrict__ out_aux) {
  if (threadIdx.x == 0 && blockIdx.x == 0) {
    float m = 0.f;
    for (int b = 0; b < BB; ++b) m += means[b];
    m *= (1.0f / BB);
    float v = 0.f;
    for (int b = 0; b < BB; ++b) { float d = means[b] - m; v += d * d; }
    v /= (float)(BB - 1);
    *out_aux = v;
  }
}

// ---------------- layernorm: f32 src (optional gather via GLOBAL idx), bf16 dst ----------------
__global__ void ln_kernel(const float* __restrict__ src,
                          const int* __restrict__ idx,
                          const float* __restrict__ scale,
                          const float* __restrict__ bias,
                          unsigned short* __restrict__ dst) {
  int r = blockIdx.x;
  const float* row;
  if (idx) {
    int t = idx[r];                 // global token index b*TT + t
    row = src + (size_t)t * DD;
  } else {
    row = src + (size_t)r * DD;
  }
  __shared__ float red[8];
  __shared__ float mv[2];
  int tid = threadIdx.x;
  float vals[4];
  float s = 0.f, ss = 0.f;
  for (int j = 0; j < 4; ++j) {
    float v = row[tid + 256 * j];
    vals[j] = v; s += v; ss += v * v;
  }
  for (int o = 32; o > 0; o >>= 1) { s += __shfl_down(s, o); ss += __shfl_down(ss, o); }
  int wid = tid >> 6, lane = tid & 63;
  if (lane == 0) { red[wid] = s; red[wid + 4] = ss; }
  __syncthreads();
  if (tid == 0) {
    float a = red[0] + red[1] + red[2] + red[3];
    float q = red[4] + red[5] + red[6] + red[7];
    float mean = a / (float)DD;
    float var = fmaxf(q / (float)DD - mean * mean, 0.f);
    mv[0] = mean; mv[1] = rsqrtf(var + 1e-5f);
  }
  __syncthreads();
  float mean = mv[0], rst = mv[1];
  unsigned short* drow = dst + (size_t)r * DD;
  for (int j = 0; j < 4; ++j) {
    int c = tid + 256 * j;
    float v = (vals[j] - mean) * rst * scale[c] + bias[c];
    drow[c] = f2bf(v);
  }
}

// ---------------- BT-form MFMA GEMM (m97 structure): acc = A[M,K] * W[N,K]^T ----------------
// linear LDS [128][32] + global_load_lds width 16, 2 barriers per K-step.
// EPI 0: Cb[row*N+col] = bf16(acc)                          (qkv)
// EPI 1: fout[row*DD+col] = xin[gidx[row]*DD+col] + acc     (x1 = x_sel + attn, f32)
// EPI 2: fout[gidx[row]*DD+col] = xin[row*DD+col] + acc     (scatter out = x1 + ffn, f32)
template <int EPI>
__launch_bounds__(256, 2)
__global__ void gemm_bt(const unsigned short* __restrict__ A,
                        const unsigned short* __restrict__ W,
                        int K, int N,
                        unsigned short* __restrict__ Cb,
                        const int* __restrict__ idx,
                        const float* __restrict__ xin,
                        float* __restrict__ fout) {
  __shared__ unsigned short As[128 * 32];
  __shared__ unsigned short Bs[128 * 32];
  int bm = blockIdx.x, bn = blockIdx.y;
  int tid = threadIdx.x;
  int wid = tid >> 6, lane = tid & 63;
  int quad = lane >> 4, l15 = lane & 15;
  int wm = (wid >> 1) * 64, wn = (wid & 1) * 64;

  f32x4 acc[4][4] = {};
  const int arow0 = bm * 128, brow0 = bn * 128;
  int srow = tid >> 2;
  int scol = (tid & 3) * 8;
  const unsigned short* Ag = A + (size_t)(arow0 + srow) * K + scol;
  const unsigned short* Wg = W + (size_t)(brow0 + srow) * K + scol;
  // wave-uniform LDS staging base: wave w covers rows 16w..16w+15 (1024B)
  unsigned short* AsW = As + (size_t)(tid & 192) * 8;
  unsigned short* BsW = Bs + (size_t)(tid & 192) * 8;

  for (int k0 = 0; k0 < K; k0 += 32) {
    __syncthreads();  // prior reads drained before overwrite
    gload16(Ag + k0, AsW);
    gload16(Ag + (size_t)64 * K + k0, AsW + 2048);
    gload16(Wg + k0, BsW);
    gload16(Wg + (size_t)64 * K + k0, BsW + 2048);
    __syncthreads();  // vmcnt(0) drain -> staged data visible
    short8 af[4], bfr[4];
    for (int t = 0; t < 4; ++t) af[t]  = *(const short8*)&As[(wm + t * 16 + l15) * 32 + quad * 8];
    for (int t = 0; t < 4; ++t) bfr[t] = *(const short8*)&Bs[(wn + t * 16 + l15) * 32 + quad * 8];
    for (int i = 0; i < 4; ++i)
      for (int j = 0; j < 4; ++j)
        acc[i][j] = __builtin_amdgcn_mfma_f32_16x16x32_bf16(af[i], bfr[j], acc[i][j], 0, 0, 0);
  }

  for (int i = 0; i < 4; ++i)
    for (int j = 0; j < 4; ++j)
      for (int r = 0; r < 4; ++r) {
        int row = arow0 + wm + i * 16 + quad * 4 + r;
        int col = brow0 + wn + j * 16 + l15;
        float v = acc[i][j][r];
        if (EPI == 0) {
          Cb[(size_t)row * N + col] = f2bf(v);
        } else if (EPI == 1) {
          int t = idx[row];
          fout[(size_t)row * DD + col] = xin[(size_t)t * DD + col] + v;
        } else {
          int t = idx[row];
          fout[(size_t)t * DD + col] = xin[(size_t)row * DD + col] + v;
        }
      }
}

// ---------------- dual-B GEMM for SwiGLU (m97 structure): g = silu(A*W1^T) * (A*W2^T) ----------------
__launch_bounds__(256, 2)
__global__ void gemm_dual(const unsigned short* __restrict__ A,
                          const unsigned short* __restrict__ W1,
                          const unsigned short* __restrict__ W2,
                          unsigned short* __restrict__ G,
                          int K, int N) {
  __shared__ unsigned short As[128 * 32];
  __shared__ unsigned short B1s[128 * 32];
  __shared__ unsigned short B2s[128 * 32];
  int bm = blockIdx.x, bn = blockIdx.y;
  int tid = threadIdx.x;
  int wid = tid >> 6, lane = tid & 63;
  int quad = lane >> 4, l15 = lane & 15;
  int wm = (wid >> 1) * 64, wn = (wid & 1) * 64;

  f32x4 acc1[4][4] = {};
  f32x4 acc2[4][4] = {};
  const int arow0 = bm * 128, brow0 = bn * 128;
  int srow = tid >> 2;
  int scol = (tid & 3) * 8;
  const unsigned short* Ag  = A  + (size_t)(arow0 + srow) * K + scol;
  const unsigned short* W1g = W1 + (size_t)(brow0 + srow) * K + scol;
  const unsigned short* W2g = W2 + (size_t)(brow0 + srow) * K + scol;
  unsigned short* AsW  = As  + (size_t)(tid & 192) * 8;
  unsigned short* B1sW = B1s + (size_t)(tid & 192) * 8;
  unsigned short* B2sW = B2s + (size_t)(tid & 192) * 8;

  for (int k0 = 0; k0 < K; k0 += 32) {
    __syncthreads();
    gload16(Ag + k0, AsW);
    gload16(Ag + (size_t)64 * K + k0, AsW + 2048);
    gload16(W1g + k0, B1sW);
    gload16(W1g + (size_t)64 * K + k0, B1sW + 2048);
    gload16(W2g + k0, B2sW);
    gload16(W2g + (size_t)64 * K + k0, B2sW + 2048);
    __syncthreads();
    short8 af[4], b1f[4], b2f[4];
    for (int t = 0; t < 4; ++t) af[t]  = *(const short8*)&As[(wm + t * 16 + l15) * 32 + quad * 8];
    for (int t = 0; t < 4; ++t) b1f[t] = *(const short8*)&B1s[(wn + t * 16 + l15) * 32 + quad * 8];
    for (int t = 0; t < 4; ++t) b2f[t] = *(const short8*)&B2s[(wn + t * 16 + l15) * 32 + quad * 8];
    for (int i = 0; i < 4; ++i)
      for (int j = 0; j < 4; ++j) {
        acc1[i][j] = __builtin_amdgcn_mfma_f32_16x16x32_bf16(af[i], b1f[j], acc1[i][j], 0, 0, 0);
        acc2[i][j] = __builtin_amdgcn_mfma_f32_16x16x32_bf16(af[i], b2f[j], acc2[i][j], 0, 0, 0);
      }
  }

  for (int i = 0; i < 4; ++i)
    for (int j = 0; j < 4; ++j)
      for (int r = 0; r < 4; ++r) {
        int row = arow0 + wm + i * 16 + quad * 4 + r;
        int col = brow0 + wn + j * 16 + l15;
        float u1 = acc1[i][j][r];
        float u2 = acc2[i][j][r];
        float sg = u1 / (1.0f + __expf(-u1));  // silu (native exp)
        G[(size_t)row * N + col] = f2bf(sg * u2);
      }
}

// ---------------- flash attention: 4 waves x 32 q-rows (2 q-frags), swapped-QK^T ----------------
// Vt uses a T2-style XOR column swizzle: write banks 8-way -> conflict-free.
// T14 prefetch, T5 setprio, exp2-domain online softmax with defer-max.

// Vt swizzled index: XOR 8-short (16B) column blocks by ((row>>3)&7).
// Same XOR on write (scalar) and read (b128) -> pure layout permutation.
__device__ __forceinline__ int vti(int r, int c) {
  return r * 68 + (c ^ (((r >> 3) & 7) << 3));
}

__launch_bounds__(256)
__global__ void attn_kernel(const unsigned short* __restrict__ qkv_all,
                            unsigned short* __restrict__ obuf_all) {
  int qb = blockIdx.x;   // 0..15 (128 q-rows each)
  int h = blockIdx.y;    // 0..15
  const unsigned short* qkv = qkv_all + (size_t)blockIdx.z * KSEL * 3 * DD;
  unsigned short* obuf = obuf_all + (size_t)blockIdx.z * KSEL * DD;
  int tid = threadIdx.x, wid = tid >> 6, lane = tid & 63;
  int quad = lane >> 4, l15 = lane & 15;

  __shared__ unsigned short Ks[64][68];        // keys x dims
  __shared__ unsigned short Vt[64 * 68];       // V^T: dims x keys, XOR-swizzled columns
  __shared__ unsigned short Ps[4][2][16][72];  // per-warp, per-q-frag P tiles

  const float SCL = 0.125f * 1.44269504f;   // scale * log2(e): exp2-domain softmax

  // per-wave 32 q-rows: frag g covers q = qb*128 + wid*32 + g*16 + l15
  short8 aq0[2], aq1[2];
#pragma unroll
  for (int g = 0; g < 2; ++g) {
    int qrow = qb * 128 + wid * 32 + g * 16 + l15;
    const unsigned short* qptr = qkv + (size_t)qrow * (3 * DD) + h * 64;
    aq0[g] = *(const short8*)(qptr + quad * 8);
    aq1[g] = *(const short8*)(qptr + 32 + quad * 8);
  }

  float m_run[2] = {-1e30f, -1e30f}, l_run[2] = {0.f, 0.f};
  f32x4 o_acc[2][4] = {};

  // staging: 256 threads cover 64 keys x 64 dims (2 x uint4 per thread per matrix)
  int skey = tid >> 2;               // 0..63
  int scol = (tid & 3) * 16;         // 0,16,32,48
  const unsigned short* kbase = qkv + DD + h * 64 + (size_t)skey * (3 * DD) + scol;
  const unsigned short* vbase = qkv + 2 * DD + h * 64 + (size_t)skey * (3 * DD) + scol;

  const int NT = KSEL / 64;
  // prologue: tile 0 K/V -> regs
  uint4 kv0 = *(const uint4*)(kbase);
  uint4 kv1 = *(const uint4*)(kbase + 8);
  uint4 vv0 = *(const uint4*)(vbase);
  uint4 vv1 = *(const uint4*)(vbase + 8);

  for (int kt = 0; kt < NT; ++kt) {
    __syncthreads();  // prior tile's LDS reads complete
    *(uint4*)&Ks[skey][scol] = kv0;
    *(uint4*)&Ks[skey][scol + 8] = kv1;
    {
      const unsigned short* vp0 = (const unsigned short*)&vv0;
      const unsigned short* vp1 = (const unsigned short*)&vv1;
#pragma unroll
      for (int j = 0; j < 8; ++j) Vt[vti(scol + j, skey)] = vp0[j];
#pragma unroll
      for (int j = 0; j < 8; ++j) Vt[vti(scol + 8 + j, skey)] = vp1[j];
    }
    __syncthreads();  // staged tile visible

    // T14: issue NEXT tile's loads now; latency hides under compute below
    if (kt + 1 < NT) {
      size_t off = (size_t)(kt + 1) * 64 * (3 * DD);
      kv0 = *(const uint4*)(kbase + off);
      kv1 = *(const uint4*)(kbase + off + 8);
      vv0 = *(const uint4*)(vbase + off);
      vv1 = *(const uint4*)(vbase + off + 8);
    }

    // S^T: st[g][t][r] = score(key = 16t + 4*quad + r, q = frag g row l15)
    f32x4 st[2][4];
    __builtin_amdgcn_s_setprio(1);
#pragma unroll
    for (int t = 0; t < 4; ++t) {
      short8 ka = *(const short8*)&Ks[t * 16 + l15][quad * 8];
      short8 kb = *(const short8*)&Ks[t * 16 + l15][32 + quad * 8];
#pragma unroll
      for (int g = 0; g < 2; ++g) {
        f32x4 z = {0.f, 0.f, 0.f, 0.f};
        z = __builtin_amdgcn_mfma_f32_16x16x32_bf16(ka, aq0[g], z, 0, 0, 0);
        z = __builtin_amdgcn_mfma_f32_16x16x32_bf16(kb, aq1[g], z, 0, 0, 0);
        st[g][t] = z;
      }
    }
    __builtin_amdgcn_s_setprio(0);

    // row max per frag: 15 in-register + cross-quad (same l15 -> same q)
    float mx[2];
#pragma unroll
    for (int g = 0; g < 2; ++g) {
      float m = fmaxf(fmaxf(st[g][0][0], st[g][0][1]), fmaxf(st[g][0][2], st[g][0][3]));
#pragma unroll
      for (int t = 1; t < 4; ++t)
        m = fmaxf(m, fmaxf(fmaxf(st[g][t][0], st[g][t][1]), fmaxf(st[g][t][2], st[g][t][3])));
      m = fmaxf(m, __shfl_xor(m, 16));
      m = fmaxf(m, __shfl_xor(m, 32));
      mx[g] = m;
    }

    // defer-max: rescale only when either frag's max grew by > 64 raw
    bool ok = (mx[0] <= m_run[0] + 64.0f) && (mx[1] <= m_run[1] + 64.0f);
    if (!__all(ok)) {
#pragma unroll
      for (int g = 0; g < 2; ++g) {
        float mnew = fmaxf(m_run[g], mx[g]);
        float alpha = exp2g((m_run[g] - mnew) * SCL);
        float a0 = __shfl(alpha, quad * 4 + 0);
        float a1 = __shfl(alpha, quad * 4 + 1);
        float a2 = __shfl(alpha, quad * 4 + 2);
        float a3 = __shfl(alpha, quad * 4 + 3);
#pragma unroll
        for (int dt = 0; dt < 4; ++dt) {
          o_acc[g][dt][0] *= a0; o_acc[g][dt][1] *= a1;
          o_acc[g][dt][2] *= a2; o_acc[g][dt][3] *= a3;
        }
        l_run[g] *= alpha;
        m_run[g] = mnew;
      }
    }

    // exp + row-sum + P->LDS per frag (packed pairs; wave-local, no barrier)
#pragma unroll
    for (int g = 0; g < 2; ++g) {
      float msc = m_run[g] * SCL;
      float ls = 0.f;
#pragma unroll
      for (int t = 0; t < 4; ++t) {
        float p0 = exp2g(__builtin_fmaf(st[g][t][0], SCL, -msc));
        float p1 = exp2g(__builtin_fmaf(st[g][t][1], SCL, -msc));
        float p2 = exp2g(__builtin_fmaf(st[g][t][2], SCL, -msc));
        float p3 = exp2g(__builtin_fmaf(st[g][t][3], SCL, -msc));
        ls += (p0 + p1) + (p2 + p3);
        unsigned int w0, w1;
        asm("v_cvt_pk_bf16_f32 %0, %1, %2" : "=v"(w0) : "v"(p0), "v"(p1));
        asm("v_cvt_pk_bf16_f32 %0, %1, %2" : "=v"(w1) : "v"(p2), "v"(p3));
        *(unsigned int*)&Ps[wid][g][l15][t * 16 + quad * 4] = w0;
        *(unsigned int*)&Ps[wid][g][l15][t * 16 + quad * 4 + 2] = w1;
      }
      ls += __shfl_xor(ls, 16);
      ls += __shfl_xor(ls, 32);
      l_run[g] += ls;
    }

    // PV: V-frags read once (swizzled), used by both q-frags
    short8 ap0[2], ap1[2];
#pragma unroll
    for (int g = 0; g < 2; ++g) {
      ap0[g] = *(const short8*)&Ps[wid][g][l15][quad * 8];
      ap1[g] = *(const short8*)&Ps[wid][g][l15][32 + quad * 8];
    }
    __builtin_amdgcn_s_setprio(1);
#pragma unroll
    for (int dt = 0; dt < 4; ++dt) {
      short8 vf0 = *(const short8*)&Vt[vti(dt * 16 + l15, quad * 8)];
      short8 vf1 = *(const short8*)&Vt[vti(dt * 16 + l15, 32 + quad * 8)];
#pragma unroll
      for (int g = 0; g < 2; ++g) {
        o_acc[g][dt] = __builtin_amdgcn_mfma_f32_16x16x32_bf16(ap0[g], vf0, o_acc[g][dt], 0, 0, 0);
        o_acc[g][dt] = __builtin_amdgcn_mfma_f32_16x16x32_bf16(ap1[g], vf1, o_acc[g][dt], 0, 0, 0);
      }
    }
    __builtin_amdgcn_s_setprio(0);
  }

  // epilogue per frag: l for o_acc's rows (q = quad*4 + r) via shfl
  unsigned short* op = obuf + h * 64;
#pragma unroll
  for (int g = 0; g < 2; ++g) {
    float rl[4];
#pragma unroll
    for (int r = 0; r < 4; ++r) rl[r] = 1.0f / __shfl(l_run[g], quad * 4 + r);
    int orow = qb * 128 + wid * 32 + g * 16 + quad * 4;
#pragma unroll
    for (int dt = 0; dt < 4; ++dt)
#pragma unroll
      for (int r = 0; r < 4; ++r) {
        float v = o_acc[g][dt][r] * rl[r];
        op[(size_t)(orow + r) * DD + dt * 16 + l15] = f2bf(v);
      }
  }
}

// ---------------- launch: batched across B with ws_size-adaptive chunking ----------------
extern "C" void kernel_launch(void* const* d_in, const int* in_sizes, int n_in,
                              void* d_out, int out_size, void* d_ws, size_t ws_size,
                              hipStream_t stream) {
  const float* x    = (const float*)d_in[0];
  const float* wr   = (const float*)d_in[1];
  const float* ln1s = (const float*)d_in[2];
  const float* ln1b = (const float*)d_in[3];
  const float* ln2s = (const float*)d_in[4];
  const float* ln2b = (const float*)d_in[5];
  const float* wqkv = (const float*)d_in[6];
  const float* wout = (const float*)d_in[7];
  const float* w1   = (const float*)d_in[8];
  const float* w2   = (const float*)d_in[9];
  const float* w3   = (const float*)d_in[10];
  float* out = (float*)d_out;
  char* ws = (char*)d_ws;

  // control region [0, 1 MiB)
  double* dots  = (double*)(ws + 0);        // 128 KiB
  float*  sig   = (float*)(ws + 131072);    // 64 KiB
  int*    flags = (int*)(ws + 196608);      // 64 KiB
  int*    idx   = (int*)(ws + 262144);      // 32 KiB (global token indices)
  float*  means = (float*)(ws + 294912);    // 16 B
  // bf16 weight copies [1 MiB, 33 MiB)
  unsigned short* wqkv_h = (unsigned short*)(ws + ((size_t)1 << 20));   // 6 MiB
  unsigned short* wout_h = (unsigned short*)(ws + ((size_t)7 << 20));   // 2 MiB
  unsigned short* w1_h   = (unsigned short*)(ws + ((size_t)9 << 20));   // 8 MiB
  unsigned short* w2_h   = (unsigned short*)(ws + ((size_t)17 << 20));  // 8 MiB
  unsigned short* w3_h   = (unsigned short*)(ws + ((size_t)25 << 20));  // 8 MiB
  const size_t base = (size_t)33 << 20;

  // merged weight conversion f32 -> bf16 (16M elements, 4/thread)
  cvt_all_kernel<<<dim3(16 * 1024 * 1024 / 1024), dim3(256), 0, stream>>>(
      wqkv, wout, w1, w2, w3, wqkv_h, wout_h, w1_h, w2_h, w3_h);

  router_kernel<<<dim3(BB * TT / 4), dim3(256), 0, stream>>>(x, wr, dots, sig);
  rank_kernel<<<dim3(BB * 16), dim3(256), 0, stream>>>(dots, flags);
  // pass-through: only unselected rows (selected overwritten by scatter later)
  copyrow_kernel<<<dim3(BB * TT), dim3(256), 0, stream>>>(x, flags, out);
  compact_kernel<<<dim3(BB), dim3(256), 0, stream>>>(flags, sig, idx, means);
  aux_kernel<<<dim3(1), dim3(64), 0, stream>>>(means, out + (size_t)BB * TT * DD);

  // per-row buffer bytes: x1 4096 + norm 2048 + max(qkv 6144 + obuf 2048, gbuf 8192) = 14336
  int cb = 4;  // batches per chunk
  while (cb > 1 && base + (size_t)cb * KSEL * 14336 > ws_size) cb >>= 1;

  for (int c0 = 0; c0 < BB; c0 += cb) {
    const int R = cb * KSEL;  // rows in this chunk
    const int* gidx = idx + (size_t)c0 * KSEL;
    float*          x1    = (float*)(ws + base);
    unsigned short* normb = (unsigned short*)(ws + base + (size_t)R * 4096);
    unsigned short* qkvb  = (unsigned short*)(ws + base + (size_t)R * 6144);
    unsigned short* obufb = (unsigned short*)(ws + base + (size_t)R * 12288);
    unsigned short* gbuf  = qkvb;  // overlays dead qkv+obuf (R*8192 <= R*6144 + R*2048)

    // ln1 on gathered selected tokens -> bf16
    ln_kernel<<<dim3(R), dim3(256), 0, stream>>>(x, gidx, ln1s, ln1b, normb);

    // qkv = normed @ w_qkv^T  (R x 3072, K=1024) -> bf16
    gemm_bt<0><<<dim3(R / 128, 3 * DD / 128), dim3(256), 0, stream>>>(
        normb, wqkv_h, DD, 3 * DD, qkvb, nullptr, nullptr, nullptr);

    // attention -> bf16 obuf (per-batch via blockIdx.z)
    attn_kernel<<<dim3(KSEL / 128, HH, cb), dim3(256), 0, stream>>>(qkvb, obufb);

    // x1 = x_sel + o @ w_out^T  -> f32
    gemm_bt<1><<<dim3(R / 128, DD / 128), dim3(256), 0, stream>>>(
        obufb, wout_h, DD, DD, nullptr, gidx, x, x1);

    // ln2 -> bf16
    ln_kernel<<<dim3(R), dim3(256), 0, stream>>>(x1, nullptr, ln2s, ln2b, normb);

    // g = silu(h@w1^T) * (h@w2^T)  (R x 4096, K=1024) -> bf16
    gemm_dual<<<dim3(R / 128, DFF / 128), dim3(256), 0, stream>>>(
        normb, w1_h, w2_h, gbuf, DD, DFF);

    // out[gidx, :] = x1 + g @ w3^T  (K=4096) -> f32 scatter
    gemm_bt<2><<<dim3(R / 128, DD / 128), dim3(256), 0, stream>>>(
        gbuf, w3_h, DFF, DD, nullptr, gidx, x1, out);
  }
}

// Round 8
// 799.357 us; speedup vs baseline: 1.0338x; 1.0338x over previous
//
#include <hip/hip_runtime.h>
#include <hip/hip_bf16.h>
#include <math.h>

#define BB 4
#define TT 4096
#define DD 1024
#define HH 16
#define DFF 4096
#define KSEL 2048

typedef __attribute__((ext_vector_type(8))) short short8;
typedef __attribute__((ext_vector_type(4))) float f32x4;

__device__ __forceinline__ unsigned short f2bf(float f) {
  union { float f; unsigned int i; } v; v.f = f;
  unsigned int x = v.i;
  unsigned int r = (x + 0x7fffu + ((x >> 16) & 1u)) >> 16;
  return (unsigned short)r;
}

// native 2^x (v_exp_f32) — avoids glibc __exp2f macro collision
__device__ __forceinline__ float exp2g(float x) { return __builtin_amdgcn_exp2f(x); }
// native 1/x (v_rcp_f32), ~1 ulp
__device__ __forceinline__ float rcpg(float x) { return __builtin_amdgcn_rcpf(x); }
// packed f32x2 -> bf16x2 (RNE, identical to f2bf)
__device__ __forceinline__ unsigned int pk2bf(float a, float b) {
  unsigned int w;
  asm("v_cvt_pk_bf16_f32 %0, %1, %2" : "=v"(w) : "v"(a), "v"(b));
  return w;
}

// async global->LDS, 16B per lane; lds ptr must be wave-uniform (lane0 = wave base)
__device__ __forceinline__ void gload16(const void* g, void* l) {
  __builtin_amdgcn_global_load_lds(
      (const __attribute__((address_space(1))) void*)g,
      (__attribute__((address_space(3))) void*)l,
      16, 0, 0);
}

// ---------------- merged f32 -> bf16 conversion for all 5 weight tensors ----------------
__global__ void cvt_all_kernel(const float* __restrict__ s0, const float* __restrict__ s1,
                               const float* __restrict__ s2, const float* __restrict__ s3,
                               const float* __restrict__ s4,
                               unsigned short* __restrict__ d0, unsigned short* __restrict__ d1,
                               unsigned short* __restrict__ d2, unsigned short* __restrict__ d3,
                               unsigned short* __restrict__ d4) {
  const long n0 = (long)3 * DD * DD;     // wqkv  3M
  const long n1 = (long)DD * DD;         // wout  1M
  const long n2 = (long)DFF * DD;        // w1/w2/w3  4M each
  long i = ((long)blockIdx.x * 256 + threadIdx.x) * 4;
  const float* src; unsigned short* dst; long off;
  if (i < n0)                    { src = s0; dst = d0; off = i; }
  else if (i < n0 + n1)          { src = s1; dst = d1; off = i - n0; }
  else if (i < n0 + n1 + n2)     { src = s2; dst = d2; off = i - n0 - n1; }
  else if (i < n0 + n1 + 2*n2)   { src = s3; dst = d3; off = i - n0 - n1 - n2; }
  else                           { src = s4; dst = d4; off = i - n0 - n1 - 2*n2; }
  float4 v = *(const float4*)(src + off);
  ushort4 o;
  o.x = f2bf(v.x); o.y = f2bf(v.y); o.z = f2bf(v.z); o.w = f2bf(v.w);
  *(ushort4*)(dst + off) = o;
}

// ---------------- router: f64 dot per token + sigmoid ----------------
__global__ void router_kernel(const float* __restrict__ x,
                              const float* __restrict__ wr,
                              double* __restrict__ dots, float* __restrict__ sig) {
  int token = blockIdx.x * 4 + (threadIdx.x >> 6);
  int lane = threadIdx.x & 63;
  const float* xr = x + (size_t)token * DD;
  double s = 0.0;
  for (int j = lane; j < DD; j += 64)
    s += (double)xr[j] * (double)wr[j];
  for (int o = 32; o > 0; o >>= 1) s += __shfl_down(s, o);
  if (lane == 0) {
    dots[token] = s;
    sig[token] = 1.0f / (1.0f + expf((float)(-s)));
  }
}

// ---------------- rank: count tokens strictly ahead; flag top-k ----------------
__global__ void rank_kernel(const double* __restrict__ dots, int* __restrict__ flags) {
  __shared__ double sd[TT];
  int b = blockIdx.x >> 4;
  int chunk = blockIdx.x & 15;
  const double* drow = dots + (size_t)b * TT;
  for (int j = threadIdx.x; j < TT; j += 256) sd[j] = drow[j];
  __syncthreads();
  int i = chunk * 256 + threadIdx.x;
  double di = sd[i];
  int cnt = 0;
  for (int j = 0; j < TT; ++j) {
    double dj = sd[j];
    cnt += (int)((dj > di) || (dj == di && j < i));
  }
  flags[(size_t)b * TT + i] = (cnt < KSEL) ? 1 : 0;
}

// ---------------- compact: ascending selected GLOBAL indices (b*TT+t) + batch mean ----------------
__global__ void compact_kernel(const int* __restrict__ flags, const float* __restrict__ sig,
                               int* __restrict__ idx, float* __restrict__ means) {
  __shared__ int part[256];
  __shared__ float ssum[256];
  int b = blockIdx.x;
  const int* f = flags + (size_t)b * TT;
  int tid = threadIdx.x;
  int local = 0; float fs = 0.f;
  for (int j = 0; j < 16; ++j) {
    local += f[tid * 16 + j];
    fs += sig[(size_t)b * TT + tid * 16 + j];
  }
  part[tid] = local; ssum[tid] = fs;
  __syncthreads();
  if (tid == 0) {
    int run = 0;
    for (int t = 0; t < 256; ++t) { int c = part[t]; part[t] = run; run += c; }
    float tot = 0.f;
    for (int t = 0; t < 256; ++t) tot += ssum[t];
    means[b] = tot / (float)TT;
  }
  __syncthreads();
  int pos = part[tid];
  for (int j = 0; j < 16; ++j) {
    int t = tid * 16 + j;
    if (f[t]) { idx[(size_t)b * KSEL + pos] = b * TT + t; ++pos; }
  }
}

__global__ void aux_kernel(const float* __restrict__ means, float* __restrict__ out_aux) {
  if (threadIdx.x == 0 && blockIdx.x == 0) {
    float m = 0.f;
    for (int b = 0; b < BB; ++b) m += means[b];
    m *= (1.0f / BB);
    float v = 0.f;
    for (int b = 0; b < BB; ++b) { float d = means[b] - m; v += d * d; }
    v /= (float)(BB - 1);
    *out_aux = v;
  }
}

// ---------------- layernorm: f32 src (optional gather via GLOBAL idx), bf16 dst ----------------
__global__ void ln_kernel(const float* __restrict__ src,
                          const int* __restrict__ idx,
                          const float* __restrict__ scale,
                          const float* __restrict__ bias,
                          unsigned short* __restrict__ dst) {
  int r = blockIdx.x;
  const float* row;
  if (idx) {
    int t = idx[r];                 // global token index b*TT + t
    row = src + (size_t)t * DD;
  } else {
    row = src + (size_t)r * DD;
  }
  __shared__ float red[8];
  __shared__ float mv[2];
  int tid = threadIdx.x;
  float vals[4];
  float s = 0.f, ss = 0.f;
  for (int j = 0; j < 4; ++j) {
    float v = row[tid + 256 * j];
    vals[j] = v; s += v; ss += v * v;
  }
  for (int o = 32; o > 0; o >>= 1) { s += __shfl_down(s, o); ss += __shfl_down(ss, o); }
  int wid = tid >> 6, lane = tid & 63;
  if (lane == 0) { red[wid] = s; red[wid + 4] = ss; }
  __syncthreads();
  if (tid == 0) {
    float a = red[0] + red[1] + red[2] + red[3];
    float q = red[4] + red[5] + red[6] + red[7];
    float mean = a / (float)DD;
    float var = fmaxf(q / (float)DD - mean * mean, 0.f);
    mv[0] = mean; mv[1] = rsqrtf(var + 1e-5f);
  }
  __syncthreads();
  float mean = mv[0], rst = mv[1];
  unsigned short* drow = dst + (size_t)r * DD;
  for (int j = 0; j < 4; ++j) {
    int c = tid + 256 * j;
    float v = (vals[j] - mean) * rst * scale[c] + bias[c];
    drow[c] = f2bf(v);
  }
}

// ---------------- BT-form MFMA GEMM (m97 structure): acc = A[M,K] * W[N,K]^T ----------------
// linear LDS [128][32] + global_load_lds width 16, 2 barriers per K-step.
// EPI 0: Cb[row*N+col] = bf16(acc)  (paired cvt_pk)         (qkv)
// EPI 1: fout[row*DD+col] = xin[gidx[row]*DD+col] + acc     (x1 = x_sel + attn, f32)
// EPI 2: fout[gidx[row]*DD+col] = xin[row*DD+col] + acc     (scatter out = x1 + ffn, f32)
template <int EPI>
__launch_bounds__(256, 2)
__global__ void gemm_bt(const unsigned short* __restrict__ A,
                        const unsigned short* __restrict__ W,
                        int K, int N,
                        unsigned short* __restrict__ Cb,
                        const int* __restrict__ idx,
                        const float* __restrict__ xin,
                        float* __restrict__ fout) {
  __shared__ unsigned short As[128 * 32];
  __shared__ unsigned short Bs[128 * 32];
  int bm = blockIdx.x, bn = blockIdx.y;
  int tid = threadIdx.x;
  int wid = tid >> 6, lane = tid & 63;
  int quad = lane >> 4, l15 = lane & 15;
  int wm = (wid >> 1) * 64, wn = (wid & 1) * 64;

  f32x4 acc[4][4] = {};
  const int arow0 = bm * 128, brow0 = bn * 128;
  int srow = tid >> 2;
  int scol = (tid & 3) * 8;
  const unsigned short* Ag = A + (size_t)(arow0 + srow) * K + scol;
  const unsigned short* Wg = W + (size_t)(brow0 + srow) * K + scol;
  // wave-uniform LDS staging base: wave w covers rows 16w..16w+15 (1024B)
  unsigned short* AsW = As + (size_t)(tid & 192) * 8;
  unsigned short* BsW = Bs + (size_t)(tid & 192) * 8;

  for (int k0 = 0; k0 < K; k0 += 32) {
    __syncthreads();  // prior reads drained before overwrite
    gload16(Ag + k0, AsW);
    gload16(Ag + (size_t)64 * K + k0, AsW + 2048);
    gload16(Wg + k0, BsW);
    gload16(Wg + (size_t)64 * K + k0, BsW + 2048);
    __syncthreads();  // vmcnt(0) drain -> staged data visible
    short8 af[4], bfr[4];
    for (int t = 0; t < 4; ++t) af[t]  = *(const short8*)&As[(wm + t * 16 + l15) * 32 + quad * 8];
    for (int t = 0; t < 4; ++t) bfr[t] = *(const short8*)&Bs[(wn + t * 16 + l15) * 32 + quad * 8];
    for (int i = 0; i < 4; ++i)
      for (int j = 0; j < 4; ++j)
        acc[i][j] = __builtin_amdgcn_mfma_f32_16x16x32_bf16(af[i], bfr[j], acc[i][j], 0, 0, 0);
  }

  for (int i = 0; i < 4; ++i)
    for (int j = 0; j < 4; ++j) {
      if (EPI == 0) {
        int col = brow0 + wn + j * 16 + l15;
        for (int r = 0; r < 4; r += 2) {
          int row = arow0 + wm + i * 16 + quad * 4 + r;
          unsigned int w = pk2bf(acc[i][j][r], acc[i][j][r + 1]);
          Cb[(size_t)row * N + col] = (unsigned short)(w & 0xffffu);
          Cb[(size_t)(row + 1) * N + col] = (unsigned short)(w >> 16);
        }
      } else {
        for (int r = 0; r < 4; ++r) {
          int row = arow0 + wm + i * 16 + quad * 4 + r;
          int col = brow0 + wn + j * 16 + l15;
          float v = acc[i][j][r];
          if (EPI == 1) {
            int t = idx[row];
            fout[(size_t)row * DD + col] = xin[(size_t)t * DD + col] + v;
          } else {
            int t = idx[row];
            fout[(size_t)t * DD + col] = xin[(size_t)row * DD + col] + v;
          }
        }
      }
    }
}

// ---------------- dual-B GEMM for SwiGLU (m97 structure): g = silu(A*W1^T) * (A*W2^T) ----------------
// epilogue: silu via native rcp (no IEEE div sequence), paired cvt_pk bf16 packing
__launch_bounds__(256, 2)
__global__ void gemm_dual(const unsigned short* __restrict__ A,
                          const unsigned short* __restrict__ W1,
                          const unsigned short* __restrict__ W2,
                          unsigned short* __restrict__ G,
                          int K, int N) {
  __shared__ unsigned short As[128 * 32];
  __shared__ unsigned short B1s[128 * 32];
  __shared__ unsigned short B2s[128 * 32];
  int bm = blockIdx.x, bn = blockIdx.y;
  int tid = threadIdx.x;
  int wid = tid >> 6, lane = tid & 63;
  int quad = lane >> 4, l15 = lane & 15;
  int wm = (wid >> 1) * 64, wn = (wid & 1) * 64;

  f32x4 acc1[4][4] = {};
  f32x4 acc2[4][4] = {};
  const int arow0 = bm * 128, brow0 = bn * 128;
  int srow = tid >> 2;
  int scol = (tid & 3) * 8;
  const unsigned short* Ag  = A  + (size_t)(arow0 + srow) * K + scol;
  const unsigned short* W1g = W1 + (size_t)(brow0 + srow) * K + scol;
  const unsigned short* W2g = W2 + (size_t)(brow0 + srow) * K + scol;
  unsigned short* AsW  = As  + (size_t)(tid & 192) * 8;
  unsigned short* B1sW = B1s + (size_t)(tid & 192) * 8;
  unsigned short* B2sW = B2s + (size_t)(tid & 192) * 8;

  for (int k0 = 0; k0 < K; k0 += 32) {
    __syncthreads();
    gload16(Ag + k0, AsW);
    gload16(Ag + (size_t)64 * K + k0, AsW + 2048);
    gload16(W1g + k0, B1sW);
    gload16(W1g + (size_t)64 * K + k0, B1sW + 2048);
    gload16(W2g + k0, B2sW);
    gload16(W2g + (size_t)64 * K + k0, B2sW + 2048);
    __syncthreads();
    short8 af[4], b1f[4], b2f[4];
    for (int t = 0; t < 4; ++t) af[t]  = *(const short8*)&As[(wm + t * 16 + l15) * 32 + quad * 8];
    for (int t = 0; t < 4; ++t) b1f[t] = *(const short8*)&B1s[(wn + t * 16 + l15) * 32 + quad * 8];
    for (int t = 0; t < 4; ++t) b2f[t] = *(const short8*)&B2s[(wn + t * 16 + l15) * 32 + quad * 8];
    for (int i = 0; i < 4; ++i)
      for (int j = 0; j < 4; ++j) {
        acc1[i][j] = __builtin_amdgcn_mfma_f32_16x16x32_bf16(af[i], b1f[j], acc1[i][j], 0, 0, 0);
        acc2[i][j] = __builtin_amdgcn_mfma_f32_16x16x32_bf16(af[i], b2f[j], acc2[i][j], 0, 0, 0);
      }
  }

  for (int i = 0; i < 4; ++i)
    for (int j = 0; j < 4; ++j) {
      int col = brow0 + wn + j * 16 + l15;
      for (int r = 0; r < 4; r += 2) {
        float u1a = acc1[i][j][r],     u2a = acc2[i][j][r];
        float u1b = acc1[i][j][r + 1], u2b = acc2[i][j][r + 1];
        // silu(u1)*u2 = u1*u2 * rcp(1+exp(-u1)); exp->inf => rcp->0 => 0 (correct limit)
        float sa = (u1a * u2a) * rcpg(1.0f + __expf(-u1a));
        float sb = (u1b * u2b) * rcpg(1.0f + __expf(-u1b));
        unsigned int w = pk2bf(sa, sb);
        int row = arow0 + wm + i * 16 + quad * 4 + r;
        G[(size_t)row * N + col] = (unsigned short)(w & 0xffffu);
        G[(size_t)(row + 1) * N + col] = (unsigned short)(w >> 16);
      }
    }
}

// ---------------- flash attention: 4 waves x 32 q-rows (2 q-frags), swapped-QK^T ----------------
// 2 q-frags per wave halve LDS fragment reads per MFMA (K/V frags amortized over 2x q).
// T14 prefetch, T5 setprio, exp2-domain online softmax with defer-max.
__launch_bounds__(256)
__global__ void attn_kernel(const unsigned short* __restrict__ qkv_all,
                            unsigned short* __restrict__ obuf_all) {
  int qb = blockIdx.x;   // 0..15 (128 q-rows each)
  int h = blockIdx.y;    // 0..15
  const unsigned short* qkv = qkv_all + (size_t)blockIdx.z * KSEL * 3 * DD;
  unsigned short* obuf = obuf_all + (size_t)blockIdx.z * KSEL * DD;
  int tid = threadIdx.x, wid = tid >> 6, lane = tid & 63;
  int quad = lane >> 4, l15 = lane & 15;

  __shared__ unsigned short Ks[64][68];        // keys x dims
  __shared__ unsigned short Vt[64][68];        // V^T: dims x keys
  __shared__ unsigned short Ps[4][2][16][72];  // per-warp, per-q-frag P tiles

  const float SCL = 0.125f * 1.44269504f;   // scale * log2(e): exp2-domain softmax

  // per-wave 32 q-rows: frag g covers q = qb*128 + wid*32 + g*16 + l15
  short8 aq0[2], aq1[2];
#pragma unroll
  for (int g = 0; g < 2; ++g) {
    int qrow = qb * 128 + wid * 32 + g * 16 + l15;
    const unsigned short* qptr = qkv + (size_t)qrow * (3 * DD) + h * 64;
    aq0[g] = *(const short8*)(qptr + quad * 8);
    aq1[g] = *(const short8*)(qptr + 32 + quad * 8);
  }

  float m_run[2] = {-1e30f, -1e30f}, l_run[2] = {0.f, 0.f};
  f32x4 o_acc[2][4] = {};

  // staging: 256 threads cover 64 keys x 64 dims (2 x uint4 per thread per matrix)
  int skey = tid >> 2;               // 0..63
  int scol = (tid & 3) * 16;         // 0,16,32,48
  const unsigned short* kbase = qkv + DD + h * 64 + (size_t)skey * (3 * DD) + scol;
  const unsigned short* vbase = qkv + 2 * DD + h * 64 + (size_t)skey * (3 * DD) + scol;

  const int NT = KSEL / 64;
  // prologue: tile 0 K/V -> regs
  uint4 kv0 = *(const uint4*)(kbase);
  uint4 kv1 = *(const uint4*)(kbase + 8);
  uint4 vv0 = *(const uint4*)(vbase);
  uint4 vv1 = *(const uint4*)(vbase + 8);

  for (int kt = 0; kt < NT; ++kt) {
    __syncthreads();  // prior tile's LDS reads complete
    *(uint4*)&Ks[skey][scol] = kv0;
    *(uint4*)&Ks[skey][scol + 8] = kv1;
    {
      const unsigned short* vp0 = (const unsigned short*)&vv0;
      const unsigned short* vp1 = (const unsigned short*)&vv1;
#pragma unroll
      for (int j = 0; j < 8; ++j) Vt[scol + j][skey] = vp0[j];
#pragma unroll
      for (int j = 0; j < 8; ++j) Vt[scol + 8 + j][skey] = vp1[j];
    }
    __syncthreads();  // staged tile visible

    // T14: issue NEXT tile's loads now; latency hides under compute below
    if (kt + 1 < NT) {
      size_t off = (size_t)(kt + 1) * 64 * (3 * DD);
      kv0 = *(const uint4*)(kbase + off);
      kv1 = *(const uint4*)(kbase + off + 8);
      vv0 = *(const uint4*)(vbase + off);
      vv1 = *(const uint4*)(vbase + off + 8);
    }

    // S^T: st[g][t][r] = score(key = 16t + 4*quad + r, q = frag g row l15)
    f32x4 st[2][4];
    __builtin_amdgcn_s_setprio(1);
#pragma unroll
    for (int t = 0; t < 4; ++t) {
      short8 ka = *(const short8*)&Ks[t * 16 + l15][quad * 8];
      short8 kb = *(const short8*)&Ks[t * 16 + l15][32 + quad * 8];
#pragma unroll
      for (int g = 0; g < 2; ++g) {
        f32x4 z = {0.f, 0.f, 0.f, 0.f};
        z = __builtin_amdgcn_mfma_f32_16x16x32_bf16(ka, aq0[g], z, 0, 0, 0);
        z = __builtin_amdgcn_mfma_f32_16x16x32_bf16(kb, aq1[g], z, 0, 0, 0);
        st[g][t] = z;
      }
    }
    __builtin_amdgcn_s_setprio(0);

    // row max per frag: 15 in-register + cross-quad (same l15 -> same q)
    float mx[2];
#pragma unroll
    for (int g = 0; g < 2; ++g) {
      float m = fmaxf(fmaxf(st[g][0][0], st[g][0][1]), fmaxf(st[g][0][2], st[g][0][3]));
#pragma unroll
      for (int t = 1; t < 4; ++t)
        m = fmaxf(m, fmaxf(fmaxf(st[g][t][0], st[g][t][1]), fmaxf(st[g][t][2], st[g][t][3])));
      m = fmaxf(m, __shfl_xor(m, 16));
      m = fmaxf(m, __shfl_xor(m, 32));
      mx[g] = m;
    }

    // defer-max: rescale only when either frag's max grew by > 64 raw
    bool ok = (mx[0] <= m_run[0] + 64.0f) && (mx[1] <= m_run[1] + 64.0f);
    if (!__all(ok)) {
#pragma unroll
      for (int g = 0; g < 2; ++g) {
        float mnew = fmaxf(m_run[g], mx[g]);
        float alpha = exp2g((m_run[g] - mnew) * SCL);
        float a0 = __shfl(alpha, quad * 4 + 0);
        float a1 = __shfl(alpha, quad * 4 + 1);
        float a2 = __shfl(alpha, quad * 4 + 2);
        float a3 = __shfl(alpha, quad * 4 + 3);
#pragma unroll
        for (int dt = 0; dt < 4; ++dt) {
          o_acc[g][dt][0] *= a0; o_acc[g][dt][1] *= a1;
          o_acc[g][dt][2] *= a2; o_acc[g][dt][3] *= a3;
        }
        l_run[g] *= alpha;
        m_run[g] = mnew;
      }
    }

    // exp + row-sum + P->LDS per frag (packed pairs; wave-local, no barrier)
#pragma unroll
    for (int g = 0; g < 2; ++g) {
      float msc = m_run[g] * SCL;
      float ls = 0.f;
#pragma unroll
      for (int t = 0; t < 4; ++t) {
        float p0 = exp2g(__builtin_fmaf(st[g][t][0], SCL, -msc));
        float p1 = exp2g(__builtin_fmaf(st[g][t][1], SCL, -msc));
        float p2 = exp2g(__builtin_fmaf(st[g][t][2], SCL, -msc));
        float p3 = exp2g(__builtin_fmaf(st[g][t][3], SCL, -msc));
        ls += (p0 + p1) + (p2 + p3);
        unsigned int w0 = pk2bf(p0, p1);
        unsigned int w1 = pk2bf(p2, p3);
        *(unsigned int*)&Ps[wid][g][l15][t * 16 + quad * 4] = w0;
        *(unsigned int*)&Ps[wid][g][l15][t * 16 + quad * 4 + 2] = w1;
      }
      ls += __shfl_xor(ls, 16);
      ls += __shfl_xor(ls, 32);
      l_run[g] += ls;
    }

    // PV: V-frags read once, used by both q-frags
    short8 ap0[2], ap1[2];
#pragma unroll
    for (int g = 0; g < 2; ++g) {
      ap0[g] = *(const short8*)&Ps[wid][g][l15][quad * 8];
      ap1[g] = *(const short8*)&Ps[wid][g][l15][32 + quad * 8];
    }
    __builtin_amdgcn_s_setprio(1);
#pragma unroll
    for (int dt = 0; dt < 4; ++dt) {
      short8 vf0 = *(const short8*)&Vt[dt * 16 + l15][quad * 8];
      short8 vf1 = *(const short8*)&Vt[dt * 16 + l15][32 + quad * 8];
#pragma unroll
      for (int g = 0; g < 2; ++g) {
        o_acc[g][dt] = __builtin_amdgcn_mfma_f32_16x16x32_bf16(ap0[g], vf0, o_acc[g][dt], 0, 0, 0);
        o_acc[g][dt] = __builtin_amdgcn_mfma_f32_16x16x32_bf16(ap1[g], vf1, o_acc[g][dt], 0, 0, 0);
      }
    }
    __builtin_amdgcn_s_setprio(0);
  }

  // epilogue per frag: l for o_acc's rows (q = quad*4 + r) via shfl; native rcp; paired cvt_pk
  unsigned short* op = obuf + h * 64;
#pragma unroll
  for (int g = 0; g < 2; ++g) {
    float rl[4];
#pragma unroll
    for (int r = 0; r < 4; ++r) rl[r] = rcpg(__shfl(l_run[g], quad * 4 + r));
    int orow = qb * 128 + wid * 32 + g * 16 + quad * 4;
#pragma unroll
    for (int dt = 0; dt < 4; ++dt) {
      int c = dt * 16 + l15;
#pragma unroll
      for (int r = 0; r < 4; r += 2) {
        float va = o_acc[g][dt][r] * rl[r];
        float vb = o_acc[g][dt][r + 1] * rl[r + 1];
        unsigned int w = pk2bf(va, vb);
        op[(size_t)(orow + r) * DD + c] = (unsigned short)(w & 0xffffu);
        op[(size_t)(orow + r + 1) * DD + c] = (unsigned short)(w >> 16);
      }
    }
  }
}

// ---------------- launch: batched across B with ws_size-adaptive chunking ----------------
extern "C" void kernel_launch(void* const* d_in, const int* in_sizes, int n_in,
                              void* d_out, int out_size, void* d_ws, size_t ws_size,
                              hipStream_t stream) {
  const float* x    = (const float*)d_in[0];
  const float* wr   = (const float*)d_in[1];
  const float* ln1s = (const float*)d_in[2];
  const float* ln1b = (const float*)d_in[3];
  const float* ln2s = (const float*)d_in[4];
  const float* ln2b = (const float*)d_in[5];
  const float* wqkv = (const float*)d_in[6];
  const float* wout = (const float*)d_in[7];
  const float* w1   = (const float*)d_in[8];
  const float* w2   = (const float*)d_in[9];
  const float* w3   = (const float*)d_in[10];
  float* out = (float*)d_out;
  char* ws = (char*)d_ws;

  // control region [0, 1 MiB)
  double* dots  = (double*)(ws + 0);        // 128 KiB
  float*  sig   = (float*)(ws + 131072);    // 64 KiB
  int*    flags = (int*)(ws + 196608);      // 64 KiB
  int*    idx   = (int*)(ws + 262144);      // 32 KiB (global token indices)
  float*  means = (float*)(ws + 294912);    // 16 B
  // bf16 weight copies [1 MiB, 33 MiB)
  unsigned short* wqkv_h = (unsigned short*)(ws + ((size_t)1 << 20));   // 6 MiB
  unsigned short* wout_h = (unsigned short*)(ws + ((size_t)7 << 20));   // 2 MiB
  unsigned short* w1_h   = (unsigned short*)(ws + ((size_t)9 << 20));   // 8 MiB
  unsigned short* w2_h   = (unsigned short*)(ws + ((size_t)17 << 20));  // 8 MiB
  unsigned short* w3_h   = (unsigned short*)(ws + ((size_t)25 << 20));  // 8 MiB
  const size_t base = (size_t)33 << 20;

  // out = x (pass-through for unselected tokens), f32, 64 MiB
  hipMemcpyAsync(out, x, (size_t)BB * TT * DD * sizeof(float),
                 hipMemcpyDeviceToDevice, stream);

  // merged weight conversion f32 -> bf16 (16M elements, 4/thread)
  cvt_all_kernel<<<dim3(16 * 1024 * 1024 / 1024), dim3(256), 0, stream>>>(
      wqkv, wout, w1, w2, w3, wqkv_h, wout_h, w1_h, w2_h, w3_h);

  router_kernel<<<dim3(BB * TT / 4), dim3(256), 0, stream>>>(x, wr, dots, sig);
  rank_kernel<<<dim3(BB * 16), dim3(256), 0, stream>>>(dots, flags);
  compact_kernel<<<dim3(BB), dim3(256), 0, stream>>>(flags, sig, idx, means);
  aux_kernel<<<dim3(1), dim3(64), 0, stream>>>(means, out + (size_t)BB * TT * DD);

  // per-row buffer bytes: x1 4096 + norm 2048 + max(qkv 6144 + obuf 2048, gbuf 8192) = 14336
  int cb = 4;  // batches per chunk
  while (cb > 1 && base + (size_t)cb * KSEL * 14336 > ws_size) cb >>= 1;

  for (int c0 = 0; c0 < BB; c0 += cb) {
    const int R = cb * KSEL;  // rows in this chunk
    const int* gidx = idx + (size_t)c0 * KSEL;
    float*          x1    = (float*)(ws + base);
    unsigned short* normb = (unsigned short*)(ws + base + (size_t)R * 4096);
    unsigned short* qkvb  = (unsigned short*)(ws + base + (size_t)R * 6144);
    unsigned short* obufb = (unsigned short*)(ws + base + (size_t)R * 12288);
    unsigned short* gbuf  = qkvb;  // overlays dead qkv+obuf (R*8192 <= R*6144 + R*2048)

    // ln1 on gathered selected tokens -> bf16
    ln_kernel<<<dim3(R), dim3(256), 0, stream>>>(x, gidx, ln1s, ln1b, normb);

    // qkv = normed @ w_qkv^T  (R x 3072, K=1024) -> bf16
    gemm_bt<0><<<dim3(R / 128, 3 * DD / 128), dim3(256), 0, stream>>>(
        normb, wqkv_h, DD, 3 * DD, qkvb, nullptr, nullptr, nullptr);

    // attention -> bf16 obuf (per-batch via blockIdx.z)
    attn_kernel<<<dim3(KSEL / 128, HH, cb), dim3(256), 0, stream>>>(qkvb, obufb);

    // x1 = x_sel + o @ w_out^T  -> f32
    gemm_bt<1><<<dim3(R / 128, DD / 128), dim3(256), 0, stream>>>(
        obufb, wout_h, DD, DD, nullptr, gidx, x, x1);

    // ln2 -> bf16
    ln_kernel<<<dim3(R), dim3(256), 0, stream>>>(x1, nullptr, ln2s, ln2b, normb);

    // g = silu(h@w1^T) * (h@w2^T)  (R x 4096, K=1024) -> bf16
    gemm_dual<<<dim3(R / 128, DFF / 128), dim3(256), 0, stream>>>(
        normb, w1_h, w2_h, gbuf, DD, DFF);

    // out[gidx, :] = x1 + g @ w3^T  (K=4096) -> f32 scatter
    gemm_bt<2><<<dim3(R / 128, DD / 128), dim3(256), 0, stream>>>(
        gbuf, w3_h, DFF, DD, nullptr, gidx, x1, out);
  }
}